// Round 4
// baseline (1628.359 us; speedup 1.0000x reference)
//
#include <hip/hip_runtime.h>
#include <hip/hip_bf16.h>

// ---------- bf16 helpers (raw ushort storage) ----------
__device__ __forceinline__ float b2f(unsigned short u) {
    union { float f; unsigned int i; } v; v.i = ((unsigned int)u) << 16; return v.f;
}
__device__ __forceinline__ unsigned short f2b(float f) {
    union { float f; unsigned int i; } v; v.f = f;
    unsigned int i = v.i;
    return (unsigned short)((i + 0x7FFFu + ((i >> 16) & 1u)) >> 16);   // RNE
}

typedef __bf16 bf16x8 __attribute__((ext_vector_type(8)));
typedef float  f32x4  __attribute__((ext_vector_type(4)));

// 256-col LDS tile: row stride 256, XOR-16B swizzle
__device__ __forceinline__ int idx256(int r, int c) {
    return r * 256 + (((c >> 3) ^ (r & 31)) << 3) + (c & 7);
}
// 128-col LDS tile
__device__ __forceinline__ int idx128(int r, int c) {
    return r * 128 + ((((c >> 3) ^ r) & 15) << 3) + (c & 7);
}

// ---------- prep: agg = 0; out[t_pred] = 0 (all fp32) ----------
template<bool BF16AGG>
__global__ __launch_bounds__(256) void prep_kernel(void* __restrict__ agg,
                                                   float* __restrict__ out, int M)
{
    int idx = blockIdx.x * 256 + threadIdx.x;          // over M*128
    if (idx < M * 128) {
        if (BF16AGG) ((unsigned short*)agg)[idx] = 0;
        else         ((float*)agg)[idx] = 0.0f;
    }
    if (idx < M) out[idx] = 0.0f;                       // t_pred = zeros
}

// ---------- scatter: agg[dst] += x_in[src] (x_in = [x | t], fp32) ----------
template<bool BF16AGG>
__global__ __launch_bounds__(256) void scatter_kernel(
    const int* __restrict__ ei, const float* __restrict__ x,
    const float* __restrict__ t, void* __restrict__ agg, int E, int M)
{
    int e = blockIdx.x * 8 + (threadIdx.x >> 5);
    if (e >= E) return;
    int lane = threadIdx.x & 31;
    int s = ei[e];
    int d = ei[E + e];
    if ((unsigned)s >= (unsigned)M || (unsigned)d >= (unsigned)M) return;  // defensive
    int f0 = lane * 4;
    const float* xr = x + (size_t)s * 127;
    float v0 = xr[f0];
    float v1 = xr[f0 + 1];
    float v2 = xr[f0 + 2];
    float v3 = (f0 + 3 < 127) ? xr[f0 + 3] : t[s];      // only lane 31 hits t
    if (BF16AGG) {
        __hip_bfloat162* dp = (__hip_bfloat162*)((unsigned short*)agg + (size_t)d * 128 + f0);
        __hip_bfloat162 a; a.x = __float2bfloat16(v0); a.y = __float2bfloat16(v1);
        __hip_bfloat162 b; b.x = __float2bfloat16(v2); b.y = __float2bfloat16(v3);
        unsafeAtomicAdd(dp,     a);
        unsafeAtomicAdd(dp + 1, b);
    } else {
        float* dp = (float*)agg + (size_t)d * 128 + f0;
        unsafeAtomicAdd(dp + 0, v0);
        unsafeAtomicAdd(dp + 1, v1);
        unsafeAtomicAdd(dp + 2, v2);
        unsafeAtomicAdd(dp + 3, v3);
    }
}

// ---------- pack fp32 weight B[K x 256] -> hi/lo bf16 planes, MFMA B order ----
// packed idx = ((kt*16 + nt)*64 + lane)*8 + j
// value      = B[(kt*32 + (lane>>4)*8 + j) * 256 + nt*16 + (lane&15)]
__global__ __launch_bounds__(256) void pack_kernel(
    const float* __restrict__ B, unsigned short* __restrict__ Bhi,
    unsigned short* __restrict__ Blo, int K)
{
    int idx = blockIdx.x * 256 + threadIdx.x;
    if (idx >= K * 256) return;
    int j    = idx & 7;
    int lane = (idx >> 3) & 63;
    int nt   = (idx >> 9) & 15;
    int kt   = idx >> 13;
    int k = kt * 32 + ((lane >> 4) * 8) + j;
    int n = nt * 16 + (lane & 15);
    float w = B[k * 256 + n];
    unsigned short hi = f2b(w);
    Bhi[idx] = hi;
    Blo[idx] = f2b(w - b2f(hi));
}

// ---------- mega: 4 GEMMs (split-bf16 weights) + final dot, LDS resident ----
template<bool BF16AGG>
__global__ __launch_bounds__(256) void mega_kernel(
    const float* __restrict__ x, const float* __restrict__ t,
    const void* __restrict__ aggv,
    const unsigned short* __restrict__ W1h, const unsigned short* __restrict__ W1l,
    const float* __restrict__ b1,
    const unsigned short* __restrict__ W2h, const unsigned short* __restrict__ W2l,
    const float* __restrict__ b2,
    const unsigned short* __restrict__ P1h, const unsigned short* __restrict__ P1l,
    const float* __restrict__ pb1,
    const unsigned short* __restrict__ P2h, const unsigned short* __restrict__ P2l,
    const float* __restrict__ pb2,
    const float* __restrict__ P3, const float* __restrict__ pb3,
    float* __restrict__ out, int M)
{
    __shared__ unsigned short S[2][64 * 256];   // 2 x 32 KB
    unsigned short* T0  = S[0];                 // h1, then p1
    unsigned short* T1  = S[1];                 // h; Tin & reduce-buf alias (disjoint lifetimes)
    unsigned short* Tin = S[1];                 // 16 KB used, stage-1 input only

    const int wave = threadIdx.x >> 6;
    const int lane = threadIdx.x & 63;
    const int lr   = lane & 15;
    const int quad = lane >> 4;
    const int lk   = quad * 8;
    const int rbase = quad * 4;
    const int row0 = blockIdx.x * 64;
    const int ntg0 = wave * 4;

    // ---- Tin = bf16(x_in + agg): 64 rows x 128 cols ----
    {
        int r = threadIdx.x >> 2;            // 0..63
        int q = threadIdx.x & 3;             // 0..3
        int gr = row0 + r; if (gr >= M) gr = M - 1;
        const float* xr = x + (size_t)gr * 127;
        #pragma unroll
        for (int c8 = 0; c8 < 4; ++c8) {
            int c0 = q * 32 + c8 * 8;
            float av[8];
            if (BF16AGG) {
                const unsigned short* ar = (const unsigned short*)aggv + (size_t)gr * 128 + c0;
                uint4 u = *(const uint4*)ar;
                av[0]=b2f((unsigned short)(u.x&0xffff)); av[1]=b2f((unsigned short)(u.x>>16));
                av[2]=b2f((unsigned short)(u.y&0xffff)); av[3]=b2f((unsigned short)(u.y>>16));
                av[4]=b2f((unsigned short)(u.z&0xffff)); av[5]=b2f((unsigned short)(u.z>>16));
                av[6]=b2f((unsigned short)(u.w&0xffff)); av[7]=b2f((unsigned short)(u.w>>16));
            } else {
                const float* ar = (const float*)aggv + (size_t)gr * 128 + c0;
                float4 g0 = *(const float4*)ar, g1 = *(const float4*)(ar + 4);
                av[0]=g0.x; av[1]=g0.y; av[2]=g0.z; av[3]=g0.w;
                av[4]=g1.x; av[5]=g1.y; av[6]=g1.z; av[7]=g1.w;
            }
            union { unsigned short u[8]; uint4 v; } ob;
            #pragma unroll
            for (int j = 0; j < 8; ++j) {
                int f = c0 + j;
                float xv = (f < 127) ? xr[f] : t[gr];
                ob.u[j] = f2b(xv + av[j]);
            }
            *(uint4*)&Tin[idx128(r, c0)] = ob.v;
        }
    }
    __syncthreads();

    f32x4 acc[4][4];
    const f32x4 zero = {0.f, 0.f, 0.f, 0.f};

    // ======== stage 1: h1 = relu(h_in @ W1 + b1) -> T0 ========
    #pragma unroll
    for (int nt = 0; nt < 4; ++nt)
        #pragma unroll
        for (int rt = 0; rt < 4; ++rt) acc[rt][nt] = zero;

    for (int kt = 0; kt < 4; ++kt) {
        bf16x8 a[4];
        #pragma unroll
        for (int rt = 0; rt < 4; ++rt)
            a[rt] = *(const bf16x8*)&Tin[idx128(rt * 16 + lr, kt * 32 + lk)];
        #pragma unroll
        for (int nt = 0; nt < 4; ++nt) {
            size_t bofs = (size_t)((kt * 16 + ntg0 + nt) * 64 + lane) * 8;
            bf16x8 bh = *(const bf16x8*)(W1h + bofs);
            bf16x8 bl = *(const bf16x8*)(W1l + bofs);
            #pragma unroll
            for (int rt = 0; rt < 4; ++rt) {
                acc[rt][nt] = __builtin_amdgcn_mfma_f32_16x16x32_bf16(a[rt], bl, acc[rt][nt], 0, 0, 0);
                acc[rt][nt] = __builtin_amdgcn_mfma_f32_16x16x32_bf16(a[rt], bh, acc[rt][nt], 0, 0, 0);
            }
        }
    }
    __syncthreads();   // Tin (T1 region) dead after this; T0 written below
    #pragma unroll
    for (int nt = 0; nt < 4; ++nt) {
        int col = (ntg0 + nt) * 16 + lr;
        float bv = b1[col];
        #pragma unroll
        for (int rt = 0; rt < 4; ++rt)
            #pragma unroll
            for (int r4 = 0; r4 < 4; ++r4)
                T0[idx256(rt * 16 + rbase + r4, col)] = f2b(fmaxf(acc[rt][nt][r4] + bv, 0.f));
    }
    __syncthreads();

    // ======== stage 2: h = tanh(relu-composed) -> T1 ========
    #pragma unroll
    for (int nt = 0; nt < 4; ++nt)
        #pragma unroll
        for (int rt = 0; rt < 4; ++rt) acc[rt][nt] = zero;

    for (int kt = 0; kt < 8; ++kt) {
        bf16x8 a[4];
        #pragma unroll
        for (int rt = 0; rt < 4; ++rt)
            a[rt] = *(const bf16x8*)&T0[idx256(rt * 16 + lr, kt * 32 + lk)];
        #pragma unroll
        for (int nt = 0; nt < 4; ++nt) {
            size_t bofs = (size_t)((kt * 16 + ntg0 + nt) * 64 + lane) * 8;
            bf16x8 bh = *(const bf16x8*)(W2h + bofs);
            bf16x8 bl = *(const bf16x8*)(W2l + bofs);
            #pragma unroll
            for (int rt = 0; rt < 4; ++rt) {
                acc[rt][nt] = __builtin_amdgcn_mfma_f32_16x16x32_bf16(a[rt], bl, acc[rt][nt], 0, 0, 0);
                acc[rt][nt] = __builtin_amdgcn_mfma_f32_16x16x32_bf16(a[rt], bh, acc[rt][nt], 0, 0, 0);
            }
        }
    }
    #pragma unroll
    for (int nt = 0; nt < 4; ++nt) {
        int col = (ntg0 + nt) * 16 + lr;
        float bv = b2[col];
        #pragma unroll
        for (int rt = 0; rt < 4; ++rt)
            #pragma unroll
            for (int r4 = 0; r4 < 4; ++r4) {
                float v = fmaxf(acc[rt][nt][r4] + bv, 0.f);   // relu(tanh(y)) == tanh(relu(y))
                float e = __expf(-2.f * v);
                T1[idx256(rt * 16 + rbase + r4, col)] = f2b((1.f - e) / (1.f + e));
            }
    }
    __syncthreads();

    // ======== stage 3: p1 = lrelu([h | x_in] @ P1 + pb1) -> T0 ========
    // x_in must be RAW (not h_in) — re-gather from x/t.
    #pragma unroll
    for (int nt = 0; nt < 4; ++nt)
        #pragma unroll
        for (int rt = 0; rt < 4; ++rt) acc[rt][nt] = zero;

    for (int kt = 0; kt < 12; ++kt) {
        bf16x8 a[4];
        if (kt < 8) {
            #pragma unroll
            for (int rt = 0; rt < 4; ++rt)
                a[rt] = *(const bf16x8*)&T1[idx256(rt * 16 + lr, kt * 32 + lk)];
        } else {
            #pragma unroll
            for (int rt = 0; rt < 4; ++rt) {
                int r = row0 + rt * 16 + lr; if (r >= M) r = M - 1;
                int c0 = (kt - 8) * 32 + lk;
                const float* xr = x + (size_t)r * 127;
                union { unsigned short u[8]; bf16x8 v; } au;
                #pragma unroll
                for (int j = 0; j < 8; ++j) {
                    int f = c0 + j;
                    au.u[j] = f2b((f < 127) ? xr[f] : t[r]);
                }
                a[rt] = au.v;
            }
        }
        #pragma unroll
        for (int nt = 0; nt < 4; ++nt) {
            size_t bofs = (size_t)((kt * 16 + ntg0 + nt) * 64 + lane) * 8;
            bf16x8 bh = *(const bf16x8*)(P1h + bofs);
            bf16x8 bl = *(const bf16x8*)(P1l + bofs);
            #pragma unroll
            for (int rt = 0; rt < 4; ++rt) {
                acc[rt][nt] = __builtin_amdgcn_mfma_f32_16x16x32_bf16(a[rt], bl, acc[rt][nt], 0, 0, 0);
                acc[rt][nt] = __builtin_amdgcn_mfma_f32_16x16x32_bf16(a[rt], bh, acc[rt][nt], 0, 0, 0);
            }
        }
    }
    __syncthreads();   // T1 reads done; T0 writes below, T1 reused as reduce buf later
    #pragma unroll
    for (int nt = 0; nt < 4; ++nt) {
        int col = (ntg0 + nt) * 16 + lr;
        float bv = pb1[col];
        #pragma unroll
        for (int rt = 0; rt < 4; ++rt)
            #pragma unroll
            for (int r4 = 0; r4 < 4; ++r4) {
                float v = acc[rt][nt][r4] + bv;
                T0[idx256(rt * 16 + rbase + r4, col)] = f2b((v > 0.f) ? v : 0.2f * v);
            }
    }
    __syncthreads();

    // ======== stage 4: p2 = lrelu(p1 @ P2 + pb2); pred = p2 . P3 + pb3 ========
    #pragma unroll
    for (int nt = 0; nt < 4; ++nt)
        #pragma unroll
        for (int rt = 0; rt < 4; ++rt) acc[rt][nt] = zero;

    for (int kt = 0; kt < 8; ++kt) {
        bf16x8 a[4];
        #pragma unroll
        for (int rt = 0; rt < 4; ++rt)
            a[rt] = *(const bf16x8*)&T0[idx256(rt * 16 + lr, kt * 32 + lk)];
        #pragma unroll
        for (int nt = 0; nt < 4; ++nt) {
            size_t bofs = (size_t)((kt * 16 + ntg0 + nt) * 64 + lane) * 8;
            bf16x8 bh = *(const bf16x8*)(P2h + bofs);
            bf16x8 bl = *(const bf16x8*)(P2l + bofs);
            #pragma unroll
            for (int rt = 0; rt < 4; ++rt) {
                acc[rt][nt] = __builtin_amdgcn_mfma_f32_16x16x32_bf16(a[rt], bl, acc[rt][nt], 0, 0, 0);
                acc[rt][nt] = __builtin_amdgcn_mfma_f32_16x16x32_bf16(a[rt], bh, acc[rt][nt], 0, 0, 0);
            }
        }
    }
    float part[4][4];
    #pragma unroll
    for (int rt = 0; rt < 4; ++rt)
        #pragma unroll
        for (int r4 = 0; r4 < 4; ++r4) part[rt][r4] = 0.f;
    #pragma unroll
    for (int nt = 0; nt < 4; ++nt) {
        int col = (ntg0 + nt) * 16 + lr;
        float bv = pb2[col];
        float p3 = P3[col];
        #pragma unroll
        for (int rt = 0; rt < 4; ++rt)
            #pragma unroll
            for (int r4 = 0; r4 < 4; ++r4) {
                float v = acc[rt][nt][r4] + bv;
                v = (v > 0.f) ? v : 0.2f * v;
                part[rt][r4] += v * p3;
            }
    }
    float* red = (float*)T1;   // T1 dead since stage-3 sync
    #pragma unroll
    for (int rt = 0; rt < 4; ++rt)
        #pragma unroll
        for (int r4 = 0; r4 < 4; ++r4) {
            float s = part[rt][r4];
            s += __shfl_xor(s, 1);
            s += __shfl_xor(s, 2);
            s += __shfl_xor(s, 4);
            s += __shfl_xor(s, 8);
            if (lr == 0) red[wave * 64 + rt * 16 + rbase + r4] = s;
        }
    __syncthreads();
    if (threadIdx.x < 64) {
        int row = row0 + threadIdx.x;
        if (row < M) {
            float s = red[threadIdx.x] + red[64 + threadIdx.x]
                    + red[128 + threadIdx.x] + red[192 + threadIdx.x] + pb3[0];
            out[M + row] = s;
        }
    }
}

extern "C" void kernel_launch(void* const* d_in, const int* in_sizes, int n_in,
                              void* d_out, int out_size, void* d_ws, size_t ws_size,
                              hipStream_t stream)
{
    const int M = in_sizes[1];                 // 50000 (t has N elements)
    const int E = in_sizes[3] / 2;             // 800000
    const float* x   = (const float*)d_in[0];
    const float* t   = (const float*)d_in[1];
    // d_in[2] = z, unused by the reference outputs
    const int*   ei  = (const int*)d_in[3];
    const float* W1  = (const float*)d_in[4];
    const float* b1  = (const float*)d_in[5];
    const float* W2  = (const float*)d_in[6];
    const float* b2  = (const float*)d_in[7];
    const float* P1  = (const float*)d_in[8];
    const float* pb1 = (const float*)d_in[9];
    const float* P2  = (const float*)d_in[10];
    const float* pb2 = (const float*)d_in[11];
    const float* P3  = (const float*)d_in[12];
    const float* pb3 = (const float*)d_in[13];
    float* out = (float*)d_out;

    // ws layout (adaptive to ws_size; branch is deterministic -> graph-safe)
    //   fp32 agg: 25.6 MB + packed weights 1 MB
    //   bf16 agg: 12.8 MB + packed weights 1 MB (fallback)
    const size_t packedElems = (size_t)(128 + 256 + 384 + 256) * 256;   // 262144
    bool f32path = ws_size >= (size_t)M * 128 * 4 + packedElems * 2 * 2 + 65536;
    size_t aggBytes = f32path ? (size_t)M * 128 * 4 : (size_t)M * 128 * 2;
    char* ws = (char*)d_ws;
    void* agg = (void*)ws;
    unsigned short* W1h = (unsigned short*)(ws + ((aggBytes + 255) & ~(size_t)255));
    unsigned short* W1l = W1h + 128 * 256;
    unsigned short* W2h = W1l + 128 * 256;
    unsigned short* W2l = W2h + 256 * 256;
    unsigned short* P1h = W2l + 256 * 256;
    unsigned short* P1l = P1h + 384 * 256;
    unsigned short* P2h = P1l + 384 * 256;
    unsigned short* P2l = P2h + 256 * 256;

    pack_kernel<<<128, 256, 0, stream>>>(W1, W1h, W1l, 128);
    pack_kernel<<<256, 256, 0, stream>>>(W2, W2h, W2l, 256);
    pack_kernel<<<384, 256, 0, stream>>>(P1, P1h, P1l, 384);
    pack_kernel<<<256, 256, 0, stream>>>(P2, P2h, P2l, 256);

    int pblocks = (M * 128 + 255) / 256;
    int sblocks = (E + 7) / 8;
    int gblocks = (M + 63) / 64;
    if (f32path) {
        prep_kernel<false><<<pblocks, 256, 0, stream>>>(agg, out, M);
        scatter_kernel<false><<<sblocks, 256, 0, stream>>>(ei, x, t, agg, E, M);
        mega_kernel<false><<<gblocks, 256, 0, stream>>>(
            x, t, agg, W1h, W1l, b1, W2h, W2l, b2,
            P1h, P1l, pb1, P2h, P2l, pb2, P3, pb3, out, M);
    } else {
        prep_kernel<true><<<pblocks, 256, 0, stream>>>(agg, out, M);
        scatter_kernel<true><<<sblocks, 256, 0, stream>>>(ei, x, t, agg, E, M);
        mega_kernel<true><<<gblocks, 256, 0, stream>>>(
            x, t, agg, W1h, W1l, b1, W2h, W2l, b2,
            P1h, P1l, pb1, P2h, P2l, pb2, P3, pb3, out, M);
    }
}

// Round 5
// 851.360 us; speedup vs baseline: 1.9127x; 1.9127x over previous
//
#include <hip/hip_runtime.h>
#include <hip/hip_bf16.h>

// ---------- bf16 helpers (raw ushort storage) ----------
__device__ __forceinline__ float b2f(unsigned short u) {
    union { float f; unsigned int i; } v; v.i = ((unsigned int)u) << 16; return v.f;
}
__device__ __forceinline__ unsigned short f2b(float f) {
    union { float f; unsigned int i; } v; v.f = f;
    unsigned int i = v.i;
    return (unsigned short)((i + 0x7FFFu + ((i >> 16) & 1u)) >> 16);   // RNE
}

typedef __bf16 bf16x8 __attribute__((ext_vector_type(8)));
typedef float  f32x4  __attribute__((ext_vector_type(4)));

// Binned-scatter geometry: 512 buckets x 98 nodes covers M=50000 (50176)
#define NB  512
#define NPB 98

// 256-col LDS tile: row stride 256, XOR-16B swizzle
__device__ __forceinline__ int idx256(int r, int c) {
    return r * 256 + (((c >> 3) ^ (r & 31)) << 3) + (c & 7);
}
// 128-col LDS tile
__device__ __forceinline__ int idx128(int r, int c) {
    return r * 128 + ((((c >> 3) ^ r) & 15) << 3) + (c & 7);
}

// ---------- out[t_pred] = 0 ----------
__global__ __launch_bounds__(256) void prep_out_kernel(float* __restrict__ out, int M)
{
    int idx = blockIdx.x * 256 + threadIdx.x;
    if (idx < M) out[idx] = 0.0f;
}

// ---------- fallback prep: agg = 0; out[t_pred] = 0 ----------
template<bool BF16AGG>
__global__ __launch_bounds__(256) void prep_kernel(void* __restrict__ agg,
                                                   float* __restrict__ out, int M)
{
    int idx = blockIdx.x * 256 + threadIdx.x;          // over M*128
    if (idx < M * 128) {
        if (BF16AGG) ((unsigned short*)agg)[idx] = 0;
        else         ((float*)agg)[idx] = 0.0f;
    }
    if (idx < M) out[idx] = 0.0f;
}

// ---------- fallback scatter: agg[dst] += x_in[src] via global atomics ----------
template<bool BF16AGG>
__global__ __launch_bounds__(256) void scatter_kernel(
    const int* __restrict__ ei, const float* __restrict__ x,
    const float* __restrict__ t, void* __restrict__ agg, int E, int M)
{
    int e = blockIdx.x * 8 + (threadIdx.x >> 5);
    if (e >= E) return;
    int lane = threadIdx.x & 31;
    int s = ei[e];
    int d = ei[E + e];
    if ((unsigned)s >= (unsigned)M || (unsigned)d >= (unsigned)M) return;
    int f0 = lane * 4;
    const float* xr = x + (size_t)s * 127;
    float v0 = xr[f0];
    float v1 = xr[f0 + 1];
    float v2 = xr[f0 + 2];
    float v3 = (f0 + 3 < 127) ? xr[f0 + 3] : t[s];
    if (BF16AGG) {
        __hip_bfloat162* dp = (__hip_bfloat162*)((unsigned short*)agg + (size_t)d * 128 + f0);
        __hip_bfloat162 a; a.x = __float2bfloat16(v0); a.y = __float2bfloat16(v1);
        __hip_bfloat162 b; b.x = __float2bfloat16(v2); b.y = __float2bfloat16(v3);
        unsafeAtomicAdd(dp,     a);
        unsafeAtomicAdd(dp + 1, b);
    } else {
        float* dp = (float*)agg + (size_t)d * 128 + f0;
        unsafeAtomicAdd(dp + 0, v0);
        unsafeAtomicAdd(dp + 1, v1);
        unsafeAtomicAdd(dp + 2, v2);
        unsafeAtomicAdd(dp + 3, v3);
    }
}

// ---------- S1: bucket histogram of dst ----------
__global__ __launch_bounds__(256) void hist_kernel(
    const int* __restrict__ ei, int* __restrict__ gcount, int E, int M)
{
    __shared__ int h[NB];
    for (int i = threadIdx.x; i < NB; i += 256) h[i] = 0;
    __syncthreads();
    for (int e = blockIdx.x * 256 + threadIdx.x; e < E; e += gridDim.x * 256) {
        int d = ei[E + e];
        int s = ei[e];
        if ((unsigned)d < (unsigned)M && (unsigned)s < (unsigned)M)
            atomicAdd(&h[d / NPB], 1);
    }
    __syncthreads();
    for (int i = threadIdx.x; i < NB; i += 256) {
        int c = h[i];
        if (c) atomicAdd(&gcount[i], c);
    }
}

// ---------- S2: exclusive scan over NB=512 bucket counts ----------
__global__ __launch_bounds__(512) void scan_kernel(
    const int* __restrict__ gcount, int* __restrict__ gstart, int* __restrict__ gcursor)
{
    __shared__ int sb[NB];
    int tid = threadIdx.x;
    int v = gcount[tid];
    sb[tid] = v;
    __syncthreads();
    for (int off = 1; off < NB; off <<= 1) {
        int a = (tid >= off) ? sb[tid - off] : 0;
        __syncthreads();
        sb[tid] += a;
        __syncthreads();
    }
    int inc = sb[tid];
    int exc = inc - v;
    gstart[tid]  = exc;
    gcursor[tid] = exc;
    if (tid == NB - 1) gstart[NB] = inc;
}

// ---------- S3: reorder edges into bucket-sorted array ----------
// sorted[slot] = (src << 7) | (dst - bucket*NPB)   (src<65536, local<128)
#define EPT3 8
__global__ __launch_bounds__(512) void reorder_kernel(
    const int* __restrict__ ei, int* __restrict__ gcursor,
    unsigned* __restrict__ sorted, int E, int M)
{
    __shared__ int cnt[NB], base[NB], cur[NB];
    for (int i = threadIdx.x; i < NB; i += 512) { cnt[i] = 0; cur[i] = 0; }
    __syncthreads();
    int mb[EPT3], ml[EPT3], ms[EPT3];
    #pragma unroll
    for (int k = 0; k < EPT3; ++k) {
        int e = blockIdx.x * (512 * EPT3) + k * 512 + threadIdx.x;
        mb[k] = -1;
        if (e < E) {
            int d = ei[E + e];
            int s = ei[e];
            if ((unsigned)d < (unsigned)M && (unsigned)s < (unsigned)M) {
                int b = d / NPB;
                mb[k] = b; ml[k] = d - b * NPB; ms[k] = s;
                atomicAdd(&cnt[b], 1);
            }
        }
    }
    __syncthreads();
    for (int i = threadIdx.x; i < NB; i += 512) {
        int c = cnt[i];
        base[i] = c ? atomicAdd(&gcursor[i], c) : 0;
    }
    __syncthreads();
    #pragma unroll
    for (int k = 0; k < EPT3; ++k) {
        if (mb[k] >= 0) {
            int slot = base[mb[k]] + atomicAdd(&cur[mb[k]], 1);
            sorted[slot] = ((unsigned)ms[k] << 7) | (unsigned)ml[k];
        }
    }
}

// ---------- S4: per-bucket LDS accumulate, coalesced agg writeback ----------
// lane j owns features {j, j+32, j+64, j+96}: LDS bank = lane -> conflict-free.
__global__ __launch_bounds__(512) void gather_bucket_kernel(
    const float* __restrict__ x, const float* __restrict__ t,
    const unsigned* __restrict__ sorted, const int* __restrict__ gstart,
    float* __restrict__ agg, int M)
{
    __shared__ float acc[NPB * 128];    // 50176 B
    for (int i = threadIdx.x; i < NPB * 128; i += 512) acc[i] = 0.f;
    __syncthreads();

    int b  = blockIdx.x;
    int s0 = gstart[b], s1 = gstart[b + 1];
    int hw = threadIdx.x >> 5;          // 0..15 half-wave id
    int lane = threadIdx.x & 31;

    int i = s0 + hw;
    unsigned u = (i < s1) ? sorted[i] : 0u;
    while (i < s1) {
        int inext = i + 16;
        unsigned unext = (inext < s1) ? sorted[inext] : 0u;   // prefetch
        int src = (int)(u >> 7);
        int l   = (int)(u & 127u);
        const float* xr = x + (size_t)src * 127;
        float v0 = xr[lane];
        float v1 = xr[lane + 32];
        float v2 = xr[lane + 64];
        float v3 = (lane == 31) ? t[src] : xr[lane + 96];
        float* ap = acc + l * 128 + lane;
        atomicAdd(ap,      v0);
        atomicAdd(ap + 32, v1);
        atomicAdd(ap + 64, v2);
        atomicAdd(ap + 96, v3);
        i = inext;
        u = unext;
    }
    __syncthreads();

    int node0 = b * NPB;
    size_t gbase = (size_t)node0 * 128;
    for (int j = threadIdx.x; j < NPB * 128; j += 512) {
        int node = node0 + (j >> 7);
        if (node < M) agg[gbase + j] = acc[j];
    }
}

// ---------- pack fp32 weight B[K x 256] -> hi/lo bf16 planes, MFMA B order ----
__global__ __launch_bounds__(256) void pack_kernel(
    const float* __restrict__ B, unsigned short* __restrict__ Bhi,
    unsigned short* __restrict__ Blo, int K)
{
    int idx = blockIdx.x * 256 + threadIdx.x;
    if (idx >= K * 256) return;
    int j    = idx & 7;
    int lane = (idx >> 3) & 63;
    int nt   = (idx >> 9) & 15;
    int kt   = idx >> 13;
    int k = kt * 32 + ((lane >> 4) * 8) + j;
    int n = nt * 16 + (lane & 15);
    float w = B[k * 256 + n];
    unsigned short hi = f2b(w);
    Bhi[idx] = hi;
    Blo[idx] = f2b(w - b2f(hi));
}

// ---------- mega: 4 GEMMs (split-bf16 weights) + final dot, LDS resident ----
template<bool BF16AGG>
__global__ __launch_bounds__(256) void mega_kernel(
    const float* __restrict__ x, const float* __restrict__ t,
    const void* __restrict__ aggv,
    const unsigned short* __restrict__ W1h, const unsigned short* __restrict__ W1l,
    const float* __restrict__ b1,
    const unsigned short* __restrict__ W2h, const unsigned short* __restrict__ W2l,
    const float* __restrict__ b2,
    const unsigned short* __restrict__ P1h, const unsigned short* __restrict__ P1l,
    const float* __restrict__ pb1,
    const unsigned short* __restrict__ P2h, const unsigned short* __restrict__ P2l,
    const float* __restrict__ pb2,
    const float* __restrict__ P3, const float* __restrict__ pb3,
    float* __restrict__ out, int M)
{
    __shared__ unsigned short S[2][64 * 256];   // 2 x 32 KB
    unsigned short* T0  = S[0];
    unsigned short* T1  = S[1];
    unsigned short* Tin = S[1];

    const int wave = threadIdx.x >> 6;
    const int lane = threadIdx.x & 63;
    const int lr   = lane & 15;
    const int quad = lane >> 4;
    const int lk   = quad * 8;
    const int rbase = quad * 4;
    const int row0 = blockIdx.x * 64;
    const int ntg0 = wave * 4;

    // ---- Tin = bf16(x_in + agg): 64 rows x 128 cols ----
    {
        int r = threadIdx.x >> 2;
        int q = threadIdx.x & 3;
        int gr = row0 + r; if (gr >= M) gr = M - 1;
        const float* xr = x + (size_t)gr * 127;
        #pragma unroll
        for (int c8 = 0; c8 < 4; ++c8) {
            int c0 = q * 32 + c8 * 8;
            float av[8];
            if (BF16AGG) {
                const unsigned short* ar = (const unsigned short*)aggv + (size_t)gr * 128 + c0;
                uint4 u = *(const uint4*)ar;
                av[0]=b2f((unsigned short)(u.x&0xffff)); av[1]=b2f((unsigned short)(u.x>>16));
                av[2]=b2f((unsigned short)(u.y&0xffff)); av[3]=b2f((unsigned short)(u.y>>16));
                av[4]=b2f((unsigned short)(u.z&0xffff)); av[5]=b2f((unsigned short)(u.z>>16));
                av[6]=b2f((unsigned short)(u.w&0xffff)); av[7]=b2f((unsigned short)(u.w>>16));
            } else {
                const float* ar = (const float*)aggv + (size_t)gr * 128 + c0;
                float4 g0 = *(const float4*)ar, g1 = *(const float4*)(ar + 4);
                av[0]=g0.x; av[1]=g0.y; av[2]=g0.z; av[3]=g0.w;
                av[4]=g1.x; av[5]=g1.y; av[6]=g1.z; av[7]=g1.w;
            }
            union { unsigned short u[8]; uint4 v; } ob;
            #pragma unroll
            for (int j = 0; j < 8; ++j) {
                int f = c0 + j;
                float xv = (f < 127) ? xr[f] : t[gr];
                ob.u[j] = f2b(xv + av[j]);
            }
            *(uint4*)&Tin[idx128(r, c0)] = ob.v;
        }
    }
    __syncthreads();

    f32x4 acc[4][4];
    const f32x4 zero = {0.f, 0.f, 0.f, 0.f};

    // ======== stage 1: h1 = relu(h_in @ W1 + b1) -> T0 ========
    #pragma unroll
    for (int nt = 0; nt < 4; ++nt)
        #pragma unroll
        for (int rt = 0; rt < 4; ++rt) acc[rt][nt] = zero;

    for (int kt = 0; kt < 4; ++kt) {
        bf16x8 a[4];
        #pragma unroll
        for (int rt = 0; rt < 4; ++rt)
            a[rt] = *(const bf16x8*)&Tin[idx128(rt * 16 + lr, kt * 32 + lk)];
        #pragma unroll
        for (int nt = 0; nt < 4; ++nt) {
            size_t bofs = (size_t)((kt * 16 + ntg0 + nt) * 64 + lane) * 8;
            bf16x8 bh = *(const bf16x8*)(W1h + bofs);
            bf16x8 bl = *(const bf16x8*)(W1l + bofs);
            #pragma unroll
            for (int rt = 0; rt < 4; ++rt) {
                acc[rt][nt] = __builtin_amdgcn_mfma_f32_16x16x32_bf16(a[rt], bl, acc[rt][nt], 0, 0, 0);
                acc[rt][nt] = __builtin_amdgcn_mfma_f32_16x16x32_bf16(a[rt], bh, acc[rt][nt], 0, 0, 0);
            }
        }
    }
    __syncthreads();
    #pragma unroll
    for (int nt = 0; nt < 4; ++nt) {
        int col = (ntg0 + nt) * 16 + lr;
        float bv = b1[col];
        #pragma unroll
        for (int rt = 0; rt < 4; ++rt)
            #pragma unroll
            for (int r4 = 0; r4 < 4; ++r4)
                T0[idx256(rt * 16 + rbase + r4, col)] = f2b(fmaxf(acc[rt][nt][r4] + bv, 0.f));
    }
    __syncthreads();

    // ======== stage 2: h = tanh(relu(h1 @ W2 + b2)) -> T1 ========
    #pragma unroll
    for (int nt = 0; nt < 4; ++nt)
        #pragma unroll
        for (int rt = 0; rt < 4; ++rt) acc[rt][nt] = zero;

    for (int kt = 0; kt < 8; ++kt) {
        bf16x8 a[4];
        #pragma unroll
        for (int rt = 0; rt < 4; ++rt)
            a[rt] = *(const bf16x8*)&T0[idx256(rt * 16 + lr, kt * 32 + lk)];
        #pragma unroll
        for (int nt = 0; nt < 4; ++nt) {
            size_t bofs = (size_t)((kt * 16 + ntg0 + nt) * 64 + lane) * 8;
            bf16x8 bh = *(const bf16x8*)(W2h + bofs);
            bf16x8 bl = *(const bf16x8*)(W2l + bofs);
            #pragma unroll
            for (int rt = 0; rt < 4; ++rt) {
                acc[rt][nt] = __builtin_amdgcn_mfma_f32_16x16x32_bf16(a[rt], bl, acc[rt][nt], 0, 0, 0);
                acc[rt][nt] = __builtin_amdgcn_mfma_f32_16x16x32_bf16(a[rt], bh, acc[rt][nt], 0, 0, 0);
            }
        }
    }
    #pragma unroll
    for (int nt = 0; nt < 4; ++nt) {
        int col = (ntg0 + nt) * 16 + lr;
        float bv = b2[col];
        #pragma unroll
        for (int rt = 0; rt < 4; ++rt)
            #pragma unroll
            for (int r4 = 0; r4 < 4; ++r4) {
                float v = fmaxf(acc[rt][nt][r4] + bv, 0.f);   // relu∘tanh == tanh∘relu
                float e = __expf(-2.f * v);
                T1[idx256(rt * 16 + rbase + r4, col)] = f2b((1.f - e) / (1.f + e));
            }
    }
    __syncthreads();

    // ======== stage 3: p1 = lrelu([h | x_in] @ P1 + pb1) -> T0 ========
    #pragma unroll
    for (int nt = 0; nt < 4; ++nt)
        #pragma unroll
        for (int rt = 0; rt < 4; ++rt) acc[rt][nt] = zero;

    for (int kt = 0; kt < 12; ++kt) {
        bf16x8 a[4];
        if (kt < 8) {
            #pragma unroll
            for (int rt = 0; rt < 4; ++rt)
                a[rt] = *(const bf16x8*)&T1[idx256(rt * 16 + lr, kt * 32 + lk)];
        } else {
            #pragma unroll
            for (int rt = 0; rt < 4; ++rt) {
                int r = row0 + rt * 16 + lr; if (r >= M) r = M - 1;
                int c0 = (kt - 8) * 32 + lk;
                const float* xr = x + (size_t)r * 127;
                union { unsigned short u[8]; bf16x8 v; } au;
                #pragma unroll
                for (int j = 0; j < 8; ++j) {
                    int f = c0 + j;
                    au.u[j] = f2b((f < 127) ? xr[f] : t[r]);
                }
                a[rt] = au.v;
            }
        }
        #pragma unroll
        for (int nt = 0; nt < 4; ++nt) {
            size_t bofs = (size_t)((kt * 16 + ntg0 + nt) * 64 + lane) * 8;
            bf16x8 bh = *(const bf16x8*)(P1h + bofs);
            bf16x8 bl = *(const bf16x8*)(P1l + bofs);
            #pragma unroll
            for (int rt = 0; rt < 4; ++rt) {
                acc[rt][nt] = __builtin_amdgcn_mfma_f32_16x16x32_bf16(a[rt], bl, acc[rt][nt], 0, 0, 0);
                acc[rt][nt] = __builtin_amdgcn_mfma_f32_16x16x32_bf16(a[rt], bh, acc[rt][nt], 0, 0, 0);
            }
        }
    }
    __syncthreads();
    #pragma unroll
    for (int nt = 0; nt < 4; ++nt) {
        int col = (ntg0 + nt) * 16 + lr;
        float bv = pb1[col];
        #pragma unroll
        for (int rt = 0; rt < 4; ++rt)
            #pragma unroll
            for (int r4 = 0; r4 < 4; ++r4) {
                float v = acc[rt][nt][r4] + bv;
                T0[idx256(rt * 16 + rbase + r4, col)] = f2b((v > 0.f) ? v : 0.2f * v);
            }
    }
    __syncthreads();

    // ======== stage 4: p2 = lrelu(p1 @ P2 + pb2); pred = p2 . P3 + pb3 ========
    #pragma unroll
    for (int nt = 0; nt < 4; ++nt)
        #pragma unroll
        for (int rt = 0; rt < 4; ++rt) acc[rt][nt] = zero;

    for (int kt = 0; kt < 8; ++kt) {
        bf16x8 a[4];
        #pragma unroll
        for (int rt = 0; rt < 4; ++rt)
            a[rt] = *(const bf16x8*)&T0[idx256(rt * 16 + lr, kt * 32 + lk)];
        #pragma unroll
        for (int nt = 0; nt < 4; ++nt) {
            size_t bofs = (size_t)((kt * 16 + ntg0 + nt) * 64 + lane) * 8;
            bf16x8 bh = *(const bf16x8*)(P2h + bofs);
            bf16x8 bl = *(const bf16x8*)(P2l + bofs);
            #pragma unroll
            for (int rt = 0; rt < 4; ++rt) {
                acc[rt][nt] = __builtin_amdgcn_mfma_f32_16x16x32_bf16(a[rt], bl, acc[rt][nt], 0, 0, 0);
                acc[rt][nt] = __builtin_amdgcn_mfma_f32_16x16x32_bf16(a[rt], bh, acc[rt][nt], 0, 0, 0);
            }
        }
    }
    float part[4][4];
    #pragma unroll
    for (int rt = 0; rt < 4; ++rt)
        #pragma unroll
        for (int r4 = 0; r4 < 4; ++r4) part[rt][r4] = 0.f;
    #pragma unroll
    for (int nt = 0; nt < 4; ++nt) {
        int col = (ntg0 + nt) * 16 + lr;
        float bv = pb2[col];
        float p3 = P3[col];
        #pragma unroll
        for (int rt = 0; rt < 4; ++rt)
            #pragma unroll
            for (int r4 = 0; r4 < 4; ++r4) {
                float v = acc[rt][nt][r4] + bv;
                v = (v > 0.f) ? v : 0.2f * v;
                part[rt][r4] += v * p3;
            }
    }
    float* red = (float*)T1;
    #pragma unroll
    for (int rt = 0; rt < 4; ++rt)
        #pragma unroll
        for (int r4 = 0; r4 < 4; ++r4) {
            float s = part[rt][r4];
            s += __shfl_xor(s, 1);
            s += __shfl_xor(s, 2);
            s += __shfl_xor(s, 4);
            s += __shfl_xor(s, 8);
            if (lr == 0) red[wave * 64 + rt * 16 + rbase + r4] = s;
        }
    __syncthreads();
    if (threadIdx.x < 64) {
        int row = row0 + threadIdx.x;
        if (row < M) {
            float s = red[threadIdx.x] + red[64 + threadIdx.x]
                    + red[128 + threadIdx.x] + red[192 + threadIdx.x] + pb3[0];
            out[M + row] = s;
        }
    }
}

extern "C" void kernel_launch(void* const* d_in, const int* in_sizes, int n_in,
                              void* d_out, int out_size, void* d_ws, size_t ws_size,
                              hipStream_t stream)
{
    const int M = in_sizes[1];                 // 50000
    const int E = in_sizes[3] / 2;             // 800000
    const float* x   = (const float*)d_in[0];
    const float* t   = (const float*)d_in[1];
    const int*   ei  = (const int*)d_in[3];
    const float* W1  = (const float*)d_in[4];
    const float* b1  = (const float*)d_in[5];
    const float* W2  = (const float*)d_in[6];
    const float* b2  = (const float*)d_in[7];
    const float* P1  = (const float*)d_in[8];
    const float* pb1 = (const float*)d_in[9];
    const float* P2  = (const float*)d_in[10];
    const float* pb2 = (const float*)d_in[11];
    const float* P3  = (const float*)d_in[12];
    const float* pb3 = (const float*)d_in[13];
    float* out = (float*)d_out;

    // ws layout (deterministic branch -> graph-safe)
    const size_t aggF32 = (size_t)M * 128 * 4;                     // 25.6 MB
    const size_t wBytes = (size_t)(128 + 256 + 384 + 256) * 256 * 2 * 2;   // 1 MB
    const size_t sortB  = (size_t)E * 4;                           // 3.2 MB
    const size_t ctrB   = (size_t)(NB + (NB + 1) + NB) * 4 + 1024;
    char* ws = (char*)d_ws;

    bool binned = (ws_size >= aggF32 + wBytes + sortB + ctrB + 4096) && (M <= NB * NPB);
    bool f32path = ws_size >= aggF32 + wBytes + 65536;

    size_t aggBytes = (binned || f32path) ? aggF32 : (size_t)M * 128 * 2;
    void* agg = (void*)ws;
    unsigned short* W1h = (unsigned short*)(ws + ((aggBytes + 255) & ~(size_t)255));
    unsigned short* W1l = W1h + 128 * 256;
    unsigned short* W2h = W1l + 128 * 256;
    unsigned short* W2l = W2h + 256 * 256;
    unsigned short* P1h = W2l + 256 * 256;
    unsigned short* P1l = P1h + 384 * 256;
    unsigned short* P2h = P1l + 384 * 256;
    unsigned short* P2l = P2h + 256 * 256;
    unsigned* sorted = (unsigned*)(P2l + 256 * 256);
    int* gcount  = (int*)(sorted + E);
    int* gstart  = gcount + NB;
    int* gcursor = gstart + NB + 1;

    pack_kernel<<<128, 256, 0, stream>>>(W1, W1h, W1l, 128);
    pack_kernel<<<256, 256, 0, stream>>>(W2, W2h, W2l, 256);
    pack_kernel<<<384, 256, 0, stream>>>(P1, P1h, P1l, 384);
    pack_kernel<<<256, 256, 0, stream>>>(P2, P2h, P2l, 256);

    int gblocks = (M + 63) / 64;
    if (binned) {
        hipMemsetAsync(gcount, 0, NB * 4, stream);
        prep_out_kernel<<<(M + 255) / 256, 256, 0, stream>>>(out, M);
        hist_kernel<<<128, 256, 0, stream>>>(ei, gcount, E, M);
        scan_kernel<<<1, 512, 0, stream>>>(gcount, gstart, gcursor);
        reorder_kernel<<<(E + 512 * EPT3 - 1) / (512 * EPT3), 512, 0, stream>>>(
            ei, gcursor, sorted, E, M);
        gather_bucket_kernel<<<NB, 512, 0, stream>>>(x, t, sorted, gstart, (float*)agg, M);
        mega_kernel<false><<<gblocks, 256, 0, stream>>>(
            x, t, agg, W1h, W1l, b1, W2h, W2l, b2,
            P1h, P1l, pb1, P2h, P2l, pb2, P3, pb3, out, M);
    } else if (f32path) {
        int pblocks = (M * 128 + 255) / 256;
        prep_kernel<false><<<pblocks, 256, 0, stream>>>(agg, out, M);
        scatter_kernel<false><<<(E + 7) / 8, 256, 0, stream>>>(ei, x, t, agg, E, M);
        mega_kernel<false><<<gblocks, 256, 0, stream>>>(
            x, t, agg, W1h, W1l, b1, W2h, W2l, b2,
            P1h, P1l, pb1, P2h, P2l, pb2, P3, pb3, out, M);
    } else {
        int pblocks = (M * 128 + 255) / 256;
        prep_kernel<true><<<pblocks, 256, 0, stream>>>(agg, out, M);
        scatter_kernel<true><<<(E + 7) / 8, 256, 0, stream>>>(ei, x, t, agg, E, M);
        mega_kernel<true><<<gblocks, 256, 0, stream>>>(
            x, t, agg, W1h, W1l, b1, W2h, W2l, b2,
            P1h, P1l, pb1, P2h, P2l, pb2, P3, pb3, out, M);
    }
}